// Round 1
// baseline (228.338 us; speedup 1.0000x reference)
//
#include <hip/hip_runtime.h>
#include <hip/hip_bf16.h>
#include <cstdint>
#include <cstddef>

// Problem constants
constexpr int Bn = 8;
constexpr int Nn = 2048;
constexpr int Dn = 128;   // IN_DIM == OUT_DIM == 128

typedef __bf16 bf16x8 __attribute__((ext_vector_type(8)));
typedef float f32x4 __attribute__((ext_vector_type(4)));

// -----------------------------------------------------------------------------
// Kernel 1: h = x @ W (fp32), s1 = h@a1, s2 = h@a2, store hT as bf16 [B][D][N]
// Block: 256 threads, 64 rows of (b,n). Grid: 16384/64 = 256 blocks.
// Thread tile: 4 rows x 8 cols, k staged in two 64-wide phases (LDS <= 64KB).
// -----------------------------------------------------------------------------
__global__ __launch_bounds__(256) void gat_k1(
    const float* __restrict__ x, const float* __restrict__ W,
    const float* __restrict__ a_vec,
    __bf16* __restrict__ hT, float* __restrict__ s1, float* __restrict__ s2) {
  __shared__ __align__(16) float Wl[64 * 132];   // [k][c], pitch 132 (16B-aligned rows)
  __shared__ __align__(16) float xT[64 * 68];    // [k][r], pitch 68  (16B-aligned rows)
  __shared__ float sred[2][4][64];               // [s1/s2][wave][row]

  const int t = threadIdx.x;
  const int r0 = blockIdx.x * 64;       // global row base over B*N
  const int b = r0 >> 11;
  const int n0 = r0 & (Nn - 1);
  const int rows = (t & 15) << 2;       // 0..60  (row base in tile)
  const int cols = (t >> 4) << 3;       // 0..120 (col base in OUT dim)

  float acc[4][8];
#pragma unroll
  for (int r = 0; r < 4; ++r)
#pragma unroll
    for (int c = 0; c < 8; ++c) acc[r][c] = 0.f;

  for (int ph = 0; ph < 2; ++ph) {
    const int k0 = ph << 6;
    __syncthreads();  // protect LDS from previous phase's readers
    // stage W[k0..k0+64)[0..128)
#pragma unroll
    for (int it = 0; it < 8; ++it) {
      int idx = t + (it << 8);          // 2048 float4 units
      int kk = idx >> 5;                // 0..63
      int c4 = (idx & 31) << 2;         // 0..124
      float4 v = *(const float4*)(W + (size_t)(k0 + kk) * Dn + c4);
      *(float4*)(Wl + kk * 132 + c4) = v;
    }
    // stage xT: x[r0+r][k0+k] -> xT[k][r] (transpose during staging)
#pragma unroll
    for (int it = 0; it < 4; ++it) {
      int idx = t + (it << 8);          // 1024 float4 units
      int r = idx >> 4;                 // 0..63
      int kc = (idx & 15) << 2;         // 0..60
      float4 v = *(const float4*)(x + (size_t)(r0 + r) * Dn + k0 + kc);
      xT[(kc + 0) * 68 + r] = v.x;
      xT[(kc + 1) * 68 + r] = v.y;
      xT[(kc + 2) * 68 + r] = v.z;
      xT[(kc + 3) * 68 + r] = v.w;
    }
    __syncthreads();
    for (int k = 0; k < 64; ++k) {
      float4 xv = *(const float4*)(xT + k * 68 + rows);
      float4 w0 = *(const float4*)(Wl + k * 132 + cols);
      float4 w1 = *(const float4*)(Wl + k * 132 + cols + 4);
      float xs[4] = {xv.x, xv.y, xv.z, xv.w};
      float ws[8] = {w0.x, w0.y, w0.z, w0.w, w1.x, w1.y, w1.z, w1.w};
#pragma unroll
      for (int r = 0; r < 4; ++r)
#pragma unroll
        for (int c = 0; c < 8; ++c) acc[r][c] = fmaf(xs[r], ws[c], acc[r][c]);
    }
  }

  // s1/s2 partials over my 8 cols, reduce across the 4 col-groups in this wave
  float a1v[8], a2v[8];
#pragma unroll
  for (int c = 0; c < 8; ++c) {
    a1v[c] = a_vec[cols + c];
    a2v[c] = a_vec[Dn + cols + c];
  }
  const int w = t >> 6;
  const int lane = t & 63;
#pragma unroll
  for (int r = 0; r < 4; ++r) {
    float q1 = 0.f, q2 = 0.f;
#pragma unroll
    for (int c = 0; c < 8; ++c) {
      q1 = fmaf(acc[r][c], a1v[c], q1);
      q2 = fmaf(acc[r][c], a2v[c], q2);
    }
    q1 += __shfl_xor(q1, 16);
    q1 += __shfl_xor(q1, 32);
    q2 += __shfl_xor(q2, 16);
    q2 += __shfl_xor(q2, 32);
    if (lane < 16) {
      sred[0][w][rows + r] = q1;
      sred[1][w][rows + r] = q2;
    }
  }
  __syncthreads();
  if (t < 64) {
    float v1 = sred[0][0][t] + sred[0][1][t] + sred[0][2][t] + sred[0][3][t];
    float v2 = sred[1][0][t] + sred[1][1][t] + sred[1][2][t] + sred[1][3][t];
    s1[b * Nn + n0 + t] = v1;
    s2[b * Nn + n0 + t] = v2;
  }
  // store hT bf16: hT[b][cols+c][n0+rows..+4]
#pragma unroll
  for (int c = 0; c < 8; ++c) {
    union { __bf16 h[4]; uint2 u; } pk;
#pragma unroll
    for (int r = 0; r < 4; ++r) pk.h[r] = (__bf16)acc[r][c];
    *(uint2*)(hT + (size_t)(b * Dn + cols + c) * Nn + n0 + rows) = pk.u;
  }
}

// -----------------------------------------------------------------------------
// Kernel 2: per (b, 32-row i-tile): softmax denominators, alpha (fp32 out +
// bf16 P tile), out-tile via mfma_f32_16x16x32_bf16. Grid: 8*64 = 512 blocks.
// Wave w: i-half (w&1)*16, d-half (w>>1)*64 (4 n-blocks of 16).
// -----------------------------------------------------------------------------
__global__ __launch_bounds__(256) void gat_k2(
    const int* __restrict__ adj, const __bf16* __restrict__ hT,
    const float* __restrict__ s1, const float* __restrict__ s2,
    float* __restrict__ out, float* __restrict__ alpha) {
  __shared__ __align__(16) float sj[Nn];          // 8 KB
  __shared__ float siv_s[32];
  __shared__ float invl_s[32];
  __shared__ __align__(16) __bf16 Pl[32 * 72];    // alpha tile, pitch 72 (144B rows)
  __shared__ __align__(16) __bf16 hl[128 * 72];   // hT tile [d][j], pitch 72

  const int t = threadIdx.x;
  const int b = blockIdx.x >> 6;
  const int i0 = (blockIdx.x & 63) << 5;

  {
    const float* s2b = s2 + b * Nn;
#pragma unroll
    for (int it = 0; it < 2; ++it) {
      int idx = (t + (it << 8)) << 2;
      *(float4*)(sj + idx) = *(const float4*)(s2b + idx);
    }
    if (t < 32) siv_s[t] = s1[b * Nn + i0 + t];
  }
  __syncthreads();

  const int ii = t >> 3, sub = t & 7;
  const int i = i0 + ii;
  const int* __restrict__ adjrow = adj + (size_t)i * Nn;
  const float si = siv_s[ii];

  // pass 1: l_i = sum_j mask * exp(lrelu(si + sj))  (no max-sub: |e| <= ~10)
  float l = 0.f;
  for (int cc = 0; cc < 16; ++cc) {
    int j0 = (sub + (cc << 3)) << 4;
    int4 a0 = *(const int4*)(adjrow + j0);
    int4 a1 = *(const int4*)(adjrow + j0 + 4);
    int4 a2 = *(const int4*)(adjrow + j0 + 8);
    int4 a3 = *(const int4*)(adjrow + j0 + 12);
    int m[16] = {a0.x, a0.y, a0.z, a0.w, a1.x, a1.y, a1.z, a1.w,
                 a2.x, a2.y, a2.z, a2.w, a3.x, a3.y, a3.z, a3.w};
#pragma unroll
    for (int q = 0; q < 16; ++q) {
      float e = si + sj[j0 + q];
      e = fmaxf(e, 0.2f * e);
      float ex = __expf(e);
      l += (m[q] > 0) ? ex : 0.f;
    }
  }
  l += __shfl_xor(l, 1);
  l += __shfl_xor(l, 2);
  l += __shfl_xor(l, 4);
  if (sub == 0) invl_s[ii] = 1.f / l;
  __syncthreads();
  const float il = invl_s[ii];

  const int lane = t & 63, w = t >> 6;
  const int iw = (w & 1) << 4;       // i-offset of my wave
  const int nb0 = (w >> 1) << 6;     // d-offset of my wave
  const int q16 = lane >> 4, m16 = lane & 15;
  f32x4 acc[4];
#pragma unroll
  for (int nb = 0; nb < 4; ++nb)
#pragma unroll
    for (int r = 0; r < 4; ++r) acc[nb][r] = 0.f;

  const __bf16* __restrict__ hTb = hT + (size_t)b * Dn * Nn;
  float* __restrict__ arow = alpha + ((size_t)(b * Nn + i) << 11);

  for (int jt = 0; jt < 32; ++jt) {
    const int j0 = jt << 6;
    // stage hT[d][j0..j0+64) -> hl
#pragma unroll
    for (int it = 0; it < 4; ++it) {
      int idx = t + (it << 8);
      int row = idx >> 3;              // 0..127
      int c8 = (idx & 7) << 3;         // 0..56
      uint4 v = *(const uint4*)(hTb + (size_t)row * Nn + j0 + c8);
      *(uint4*)(hl + row * 72 + c8) = v;
    }
    // alpha for my 8 j's (fp32 to global, bf16 to Pl)
    {
      int jj = sub << 3;
      int j = j0 + jj;
      int4 a0 = *(const int4*)(adjrow + j);
      int4 a1 = *(const int4*)(adjrow + j + 4);
      int m[8] = {a0.x, a0.y, a0.z, a0.w, a1.x, a1.y, a1.z, a1.w};
      float av[8];
#pragma unroll
      for (int qq = 0; qq < 8; ++qq) {
        float e = si + sj[j + qq];
        e = fmaxf(e, 0.2f * e);
        float al = __expf(e) * il;
        av[qq] = (m[qq] > 0) ? al : 0.f;
      }
      float4 f0 = make_float4(av[0], av[1], av[2], av[3]);
      float4 f1 = make_float4(av[4], av[5], av[6], av[7]);
      *(float4*)(arow + j) = f0;
      *(float4*)(arow + j + 4) = f1;
      union { __bf16 h[8]; uint4 u; } pk;
#pragma unroll
      for (int qq = 0; qq < 8; ++qq) pk.h[qq] = (__bf16)av[qq];
      *(uint4*)(Pl + ii * 72 + jj) = pk.u;
    }
    __syncthreads();
    // MFMA: out[i0+iw.., nb0..] += P(16x64) @ hT'(64x64-slice)
#pragma unroll
    for (int ks = 0; ks < 2; ++ks) {
      bf16x8 af = *(const bf16x8*)(Pl + (iw + m16) * 72 + (ks << 5) + (q16 << 3));
#pragma unroll
      for (int nb = 0; nb < 4; ++nb) {
        bf16x8 bf = *(const bf16x8*)(hl + (nb0 + (nb << 4) + m16) * 72 + (ks << 5) + (q16 << 3));
        acc[nb] = __builtin_amdgcn_mfma_f32_16x16x32_bf16(af, bf, acc[nb], 0, 0, 0);
      }
    }
    __syncthreads();
  }
  // epilogue: D[row=(lane>>4)*4+r][col=lane&15], row->i, col->d
#pragma unroll
  for (int nb = 0; nb < 4; ++nb) {
    int d = nb0 + (nb << 4) + m16;
#pragma unroll
    for (int r = 0; r < 4; ++r) {
      int irow = i0 + iw + (q16 << 2) + r;
      out[((size_t)(b * Nn + irow) << 7) + d] = acc[nb][r];
    }
  }
}

extern "C" void kernel_launch(void* const* d_in, const int* in_sizes, int n_in,
                              void* d_out, int out_size, void* d_ws, size_t ws_size,
                              hipStream_t stream) {
  const float* x = (const float*)d_in[0];
  const int* adj = (const int*)d_in[1];
  const float* W = (const float*)d_in[2];
  const float* a_vec = (const float*)d_in[3];

  float* out = (float*)d_out;
  float* alpha = out + (size_t)Bn * Nn * Dn;  // outputs concatenated: (out, alpha)

  char* ws = (char*)d_ws;
  __bf16* hT = (__bf16*)ws;                               // B*D*N bf16 = 4 MiB
  float* s1 = (float*)(ws + (size_t)Bn * Dn * Nn * 2);    // B*N fp32
  float* s2 = s1 + (size_t)Bn * Nn;                       // B*N fp32

  gat_k1<<<256, 256, 0, stream>>>(x, W, a_vec, hT, s1, s2);
  gat_k2<<<512, 256, 0, stream>>>(adj, hT, s1, s2, out, alpha);
}

// Round 2
// 194.075 us; speedup vs baseline: 1.1765x; 1.1765x over previous
//
#include <hip/hip_runtime.h>
#include <hip/hip_bf16.h>
#include <cstdint>
#include <cstddef>

constexpr int Bn = 8;
constexpr int Nn = 2048;
constexpr int Dn = 128;

typedef __bf16 bf16x8 __attribute__((ext_vector_type(8)));
typedef float f32x4 __attribute__((ext_vector_type(4)));

#define AS1 __attribute__((address_space(1)))
#define AS3 __attribute__((address_space(3)))

// async global->LDS, 16B per lane; LDS dest must be wave-uniform base (+lane*16)
static __device__ __forceinline__ void gl_lds16(const void* g, void* l) {
  __builtin_amdgcn_global_load_lds((AS1 const void*)g, (AS3 void*)l, 16, 0, 0);
}

// -----------------------------------------------------------------------------
// Kernel 1: h = x@W (fp32), s1 = h@a1, s2 = h@a2, hT bf16 [B][D][N].
// 512 blocks x 256 thr; 32 rows/block; thread tile 2 rows x 8 cols.
// LDS: full x-tile (32x128 fp32), W staged in two 64-k phases (swizzled pitch).
// -----------------------------------------------------------------------------
__global__ __launch_bounds__(256) void gat_k1(
    const float* __restrict__ x, const float* __restrict__ W,
    const float* __restrict__ a_vec,
    __bf16* __restrict__ hT, float* __restrict__ s1, float* __restrict__ s2) {
  __shared__ __align__(16) float Wl[64 * 144];  // [k][c-swizzled], 36.9KB
  __shared__ __align__(16) float xL[32 * 132];  // [r][k], 16.9KB

  const int t = threadIdx.x;
  const int r0 = blockIdx.x * 32;
  const int b = r0 >> 11;
  const int n0 = r0 & (Nn - 1);
  const int rp = (t >> 4) << 1;                 // row pair base 0..30
  const int c0 = (t & 15) << 3;                 // 0..120
  const int c0p = c0 + ((c0 >> 5) << 2);        // pad 4 dwords every 32 (breaks bank cycle)

  float acc[2][8];
#pragma unroll
  for (int r = 0; r < 2; ++r)
#pragma unroll
    for (int c = 0; c < 8; ++c) acc[r][c] = 0.f;

  // stage xL: 32x128 fp32
#pragma unroll
  for (int it = 0; it < 4; ++it) {
    int idx = t + (it << 8);
    int rr = idx >> 5, kc = (idx & 31) << 2;
    *(float4*)(xL + rr * 132 + kc) = *(const float4*)(x + (size_t)(r0 + rr) * Dn + kc);
  }

  for (int ph = 0; ph < 2; ++ph) {
    if (ph) __syncthreads();  // phase-0 readers done before restage
#pragma unroll
    for (int it = 0; it < 8; ++it) {
      int idx = t + (it << 8);
      int kk = idx >> 5, c4 = (idx & 31) << 2;
      int dsto = kk * 144 + c4 + ((c4 >> 5) << 2);
      *(float4*)(Wl + dsto) = *(const float4*)(W + (size_t)((ph << 6) + kk) * Dn + c4);
    }
    __syncthreads();
    const float* xrow = xL + rp * 132 + (ph << 6);
    for (int k = 0; k < 64; ++k) {
      float xa0 = xrow[k];
      float xa1 = xrow[132 + k];
      float4 w0 = *(const float4*)(Wl + k * 144 + c0p);
      float4 w1 = *(const float4*)(Wl + k * 144 + c0p + 4);
      float ws[8] = {w0.x, w0.y, w0.z, w0.w, w1.x, w1.y, w1.z, w1.w};
#pragma unroll
      for (int c = 0; c < 8; ++c) {
        acc[0][c] = fmaf(xa0, ws[c], acc[0][c]);
        acc[1][c] = fmaf(xa1, ws[c], acc[1][c]);
      }
    }
  }

  // s1/s2: partial dots over my 8 cols, reduce across 16 col-groups (lanes&15)
  float q1[2] = {0.f, 0.f}, q2[2] = {0.f, 0.f};
#pragma unroll
  for (int c = 0; c < 8; ++c) {
    float a1c = a_vec[c0 + c];
    float a2c = a_vec[Dn + c0 + c];
    q1[0] = fmaf(acc[0][c], a1c, q1[0]);
    q1[1] = fmaf(acc[1][c], a1c, q1[1]);
    q2[0] = fmaf(acc[0][c], a2c, q2[0]);
    q2[1] = fmaf(acc[1][c], a2c, q2[1]);
  }
#pragma unroll
  for (int d = 1; d < 16; d <<= 1) {
    q1[0] += __shfl_xor(q1[0], d);
    q1[1] += __shfl_xor(q1[1], d);
    q2[0] += __shfl_xor(q2[0], d);
    q2[1] += __shfl_xor(q2[1], d);
  }
  if ((t & 15) == 0) {
    s1[b * Nn + n0 + rp] = q1[0];
    s1[b * Nn + n0 + rp + 1] = q1[1];
    s2[b * Nn + n0 + rp] = q2[0];
    s2[b * Nn + n0 + rp + 1] = q2[1];
  }

  // hT store: rows rp/rp+1 are adjacent n -> pack 2 bf16 per u32
#pragma unroll
  for (int c = 0; c < 8; ++c) {
    union { __bf16 h[2]; uint32_t u; } pk;
    pk.h[0] = (__bf16)acc[0][c];
    pk.h[1] = (__bf16)acc[1][c];
    *(uint32_t*)(hT + (size_t)(b * Dn + c0 + c) * Nn + n0 + rp) = pk.u;
  }
}

// -----------------------------------------------------------------------------
// Kernel 2: per (b, 32 i-rows): softmax denom, alpha (fp32 out + bf16 P),
// out via mfma_f32_16x16x32_bf16. 512 blocks x 512 thr (8 waves).
// hl double-buffered via global_load_lds (16B), XOR-swizzled chunks.
// Wave w: i-half (w&1)*16, d-range (w>>1)*32.
// -----------------------------------------------------------------------------
__global__ __launch_bounds__(512) void gat_k2(
    const int* __restrict__ adj, const __bf16* __restrict__ hT,
    const float* __restrict__ s1, const float* __restrict__ s2,
    float* __restrict__ out, float* __restrict__ alpha) {
  __shared__ __align__(16) float sj[Nn];            // 8 KB
  __shared__ float siv[32], invl[32];
  __shared__ __align__(16) __bf16 Pl[2][32 * 72];   // 9 KB, padded pitch
  __shared__ __align__(16) __bf16 hl[2][128 * 64];  // 32 KB, swizzled

  const int t = threadIdx.x;
  const int b = blockIdx.x >> 6;
  const int i0 = (blockIdx.x & 63) << 5;
  const int w = t >> 6, lane = t & 63;
  const int ii = t >> 4, sub = t & 15;
  const int lrow = lane >> 3, ccs = lane & 7;
  const __bf16* __restrict__ hTb = hT + (size_t)b * Dn * Nn;

  // prologue: prefetch j-tile 0 into hl[0] (completes by first barrier's drain)
#pragma unroll
  for (int inst = 0; inst < 2; ++inst) {
    int row = (w << 4) + (inst << 3) + lrow;
    gl_lds16(hTb + (size_t)row * Nn + ((ccs ^ lrow) << 3),
             &hl[0][((w << 4) + (inst << 3)) << 6]);
  }

  *(float4*)(sj + (t << 2)) = *(const float4*)(s2 + b * Nn + (t << 2));
  if (t < 32) siv[t] = s1[b * Nn + i0 + t];
  __syncthreads();

  const int i = i0 + ii;
  const int* __restrict__ adjrow = adj + (size_t)i * Nn;
  const float si = siv[ii];

  // pass 1: l_i = sum_j mask * exp(lrelu(si+sj)); thread covers j = cc*64 + sub*4
  float l = 0.f;
  for (int cc = 0; cc < 32; ++cc) {
    int j = (cc << 6) + (sub << 2);
    int4 am = *(const int4*)(adjrow + j);
    float4 sv = *(const float4*)(sj + j);
    float e;
    e = si + sv.x; e = fmaxf(e, 0.2f * e); l += (am.x > 0) ? __expf(e) : 0.f;
    e = si + sv.y; e = fmaxf(e, 0.2f * e); l += (am.y > 0) ? __expf(e) : 0.f;
    e = si + sv.z; e = fmaxf(e, 0.2f * e); l += (am.z > 0) ? __expf(e) : 0.f;
    e = si + sv.w; e = fmaxf(e, 0.2f * e); l += (am.w > 0) ? __expf(e) : 0.f;
  }
  l += __shfl_xor(l, 1);
  l += __shfl_xor(l, 2);
  l += __shfl_xor(l, 4);
  l += __shfl_xor(l, 8);
  if (sub == 0) invl[ii] = 1.f / l;
  __syncthreads();
  const float il = invl[ii];

  const int iw = (w & 1) << 4;
  const int nd0 = (w >> 1) << 5;
  const int q16 = lane >> 4, m16 = lane & 15;
  f32x4 acc0 = {0.f, 0.f, 0.f, 0.f}, acc1 = {0.f, 0.f, 0.f, 0.f};
  float* __restrict__ arow = alpha + ((size_t)(b * Nn + i) << 11);

  for (int jt = 0; jt < 32; ++jt) {
    const int buf = jt & 1;
    const int j0 = jt << 6;
    // alpha for my 4 j's: fp32 -> global, bf16 -> Pl[buf]
    {
      int j = j0 + (sub << 2);
      int4 am = *(const int4*)(adjrow + j);
      float4 sv = *(const float4*)(sj + j);
      float e0 = si + sv.x; e0 = fmaxf(e0, 0.2f * e0);
      float e1 = si + sv.y; e1 = fmaxf(e1, 0.2f * e1);
      float e2 = si + sv.z; e2 = fmaxf(e2, 0.2f * e2);
      float e3 = si + sv.w; e3 = fmaxf(e3, 0.2f * e3);
      float a0 = (am.x > 0) ? __expf(e0) * il : 0.f;
      float a1 = (am.y > 0) ? __expf(e1) * il : 0.f;
      float a2 = (am.z > 0) ? __expf(e2) * il : 0.f;
      float a3 = (am.w > 0) ? __expf(e3) * il : 0.f;
      *(float4*)(arow + j) = make_float4(a0, a1, a2, a3);
      union { __bf16 h[4]; uint2 u; } pk;
      pk.h[0] = (__bf16)a0; pk.h[1] = (__bf16)a1;
      pk.h[2] = (__bf16)a2; pk.h[3] = (__bf16)a3;
      *(uint2*)(&Pl[buf][ii * 72 + (sub << 2)]) = pk.u;
    }
    __syncthreads();  // hl[buf] loads drained; Pl[buf] visible; prev MFMA reads done
    // prefetch next tile into hl[buf^1] (issued a full alpha-phase before its barrier)
    if (jt < 31) {
      int jn = j0 + 64;
#pragma unroll
      for (int inst = 0; inst < 2; ++inst) {
        int row = (w << 4) + (inst << 3) + lrow;
        gl_lds16(hTb + (size_t)row * Nn + jn + ((ccs ^ lrow) << 3),
                 &hl[buf ^ 1][((w << 4) + (inst << 3)) << 6]);
      }
    }
    // MFMA: out[i0+iw..+16, nd0..+32] += P(16xK) @ hT-slices
#pragma unroll
    for (int ks = 0; ks < 2; ++ks) {
      bf16x8 af = *(const bf16x8*)(&Pl[buf][(iw + m16) * 72 + (ks << 5) + (q16 << 3)]);
      {
        int d = nd0 + m16;
        int phys = ((ks << 2) + q16) ^ (d & 7);
        bf16x8 bv = *(const bf16x8*)(&hl[buf][(d << 6) + (phys << 3)]);
        acc0 = __builtin_amdgcn_mfma_f32_16x16x32_bf16(af, bv, acc0, 0, 0, 0);
      }
      {
        int d = nd0 + 16 + m16;
        int phys = ((ks << 2) + q16) ^ (d & 7);
        bf16x8 bv = *(const bf16x8*)(&hl[buf][(d << 6) + (phys << 3)]);
        acc1 = __builtin_amdgcn_mfma_f32_16x16x32_bf16(af, bv, acc1, 0, 0, 0);
      }
    }
  }

  // epilogue: D[row=(lane>>4)*4+r][col=lane&15]; row->i, col->d
#pragma unroll
  for (int nb = 0; nb < 2; ++nb) {
    f32x4 a = nb ? acc1 : acc0;
    int d = nd0 + (nb << 4) + m16;
#pragma unroll
    for (int r = 0; r < 4; ++r) {
      int irow = i0 + iw + (q16 << 2) + r;
      out[((size_t)(b * Nn + irow) << 7) + d] = a[r];
    }
  }
}

extern "C" void kernel_launch(void* const* d_in, const int* in_sizes, int n_in,
                              void* d_out, int out_size, void* d_ws, size_t ws_size,
                              hipStream_t stream) {
  const float* x = (const float*)d_in[0];
  const int* adj = (const int*)d_in[1];
  const float* W = (const float*)d_in[2];
  const float* a_vec = (const float*)d_in[3];

  float* out = (float*)d_out;
  float* alpha = out + (size_t)Bn * Nn * Dn;  // outputs concatenated: (out, alpha)

  char* ws = (char*)d_ws;
  __bf16* hT = (__bf16*)ws;                               // B*D*N bf16 = 4 MiB
  float* s1 = (float*)(ws + (size_t)Bn * Dn * Nn * 2);    // B*N fp32
  float* s2 = s1 + (size_t)Bn * Nn;                       // B*N fp32

  gat_k1<<<512, 256, 0, stream>>>(x, W, a_vec, hT, s1, s2);
  gat_k2<<<512, 512, 0, stream>>>(adj, hT, s1, s2, out, alpha);
}